// Round 1
// baseline (292.368 us; speedup 1.0000x reference)
//
#include <hip/hip_runtime.h>

#define PCNT 128
#define RCdim 256
#define IMG (RCdim*RCdim)
#define PITCH 40        // tile pitch in floats (160B, multiple of 16B)
#define TROWS 36        // tile rows: 32 + 2*ext2
#define TELEMS (TROWS*PITCH)
#define NTHREADS 256

__device__ __forceinline__ float sig_(float x){ return 1.0f/(1.0f+__expf(-x)); }
__device__ __forceinline__ float th_(float x){ float e=__expf(2.0f*x); return 1.0f-2.0f/(e+1.0f); }

// Stage a 36x40 fp32 tile of plant image `src`, covering global rows [R0-2,R0+33],
// cols [C0-3, C0+36], zero-padded out of bounds. Row-major, pitch 40.
__device__ __forceinline__ void stage_tile(const float* __restrict__ src, float* __restrict__ dst,
                                           int R0, int C0, int tid){
  for (int idx = tid; idx < TELEMS; idx += NTHREADS) {
    int rr = idx / PITCH;
    int cc = idx - rr*PITCH;
    int gr = R0 - 2 + rr;
    int gc = C0 - 3 + cc;
    float v = 0.0f;
    if ((unsigned)gr < RCdim && (unsigned)gc < RCdim) v = src[gr*RCdim + gc];
    dst[idx] = v;
  }
}

// Load 3 rows x 8 cols (two aligned float4 = ds_read_b128 each) starting (row0, col0).
__device__ __forceinline__ void load_rows(const float* __restrict__ T, int row0, int col0, float v[3][8]){
#pragma unroll
  for (int dy=0; dy<3; ++dy){
    const float4* pB = (const float4*)&T[(row0+dy)*PITCH + col0];
    float4 A = pB[0], B = pB[1];
    v[dy][0]=A.x; v[dy][1]=A.y; v[dy][2]=A.z; v[dy][3]=A.w;
    v[dy][4]=B.x; v[dy][5]=B.y; v[dy][6]=B.z; v[dy][7]=B.w;
  }
}

// 3x3 cross-correlation accumulate for a 1x4 strip.
// Pixel k reads v[ky][k + kx + OFF]; OFF=2 for main phase (strip base col tcol,
// pixel abs col = tcol+3+k), OFF=1 for hr phase (base 4s, position col 4s+2+k).
template<int OFF>
__device__ __forceinline__ void conv_acc(const float v[3][8], const float w9[9], float o[4]){
#pragma unroll
  for (int ky=0; ky<3; ++ky)
#pragma unroll
    for (int kx=0; kx<3; ++kx){
      const float w = w9[ky*3+kx];
#pragma unroll
      for (int k=0;k<4;++k) o[k] = fmaf(w, v[ky][k+kx+OFF], o[k]);
    }
}

__device__ __forceinline__ void load_w18(const float* __restrict__ g, float w0[9], float w1[9]){
#pragma unroll
  for (int i=0;i<9;++i){ w0[i]=g[i]; w1[i]=g[9+i]; }
}

extern "C" __global__ void init_out(const float* __restrict__ bias, float* __restrict__ out){
  int i = blockIdx.x * NTHREADS + threadIdx.x;
  out[i] = bias[i];
}

extern "C" __global__ void __launch_bounds__(NTHREADS, 2)
gru_fused(const float* __restrict__ x, const float* __restrict__ h,
          const float* __restrict__ w_reset, const float* __restrict__ b_reset,
          const float* __restrict__ w_update, const float* __restrict__ b_update,
          const float* __restrict__ w_out, const float* __restrict__ b_out,
          const float* __restrict__ w_read, float* __restrict__ out)
{
  __shared__ float sm[8][TELEMS];  // 46080 B
  const int tid  = threadIdx.x;
  const int bid  = blockIdx.x;
  const int pg   = bid & 7;         // plant group
  const int tile = bid >> 3;        // 0..63
  const int R0 = (tile >> 3) * 32;
  const int C0 = (tile & 7) * 32;
  const int trow = tid >> 3;        // 0..31
  const int tcol = (tid & 7) * 4;   // 0,4,...,28
  const int gidx = (R0 + trow) * RCdim + C0 + tcol;

  float acc[4] = {0.f,0.f,0.f,0.f};

  // ---------------- low plants: p = 8*pg + i (< 64) ----------------
  // stacked channels (2p, 2p+1) are both from x; h_p only blends at center.
  for (int i = 0; i < 8; ++i) {
    const int p = 8*pg + i;
    __syncthreads();  // protect LDS from previous iteration's readers
    stage_tile(x + (size_t)(2*p)*IMG,   sm[0], R0, C0, tid);
    stage_tile(x + (size_t)(2*p+1)*IMG, sm[1], R0, C0, tid);
    __syncthreads();

    float wu0[9],wu1[9],wo0[9],wo1[9];
    load_w18(w_update + p*18, wu0, wu1);
    load_w18(w_out    + p*18, wo0, wo1);
    const float bu = b_update[p], bo = b_out[p];

    float v0[3][8], v1[3][8];
    load_rows(sm[0], trow+1, tcol, v0);
    load_rows(sm[1], trow+1, tcol, v1);
    float uo[4] = {bu,bu,bu,bu};
    conv_acc<2>(v0, wu0, uo); conv_acc<2>(v1, wu1, uo);
    float co[4] = {bo,bo,bo,bo};
    conv_acc<2>(v0, wo0, co); conv_acc<2>(v1, wo1, co);

    const float4 hv4 = *(const float4*)&h[(size_t)p*IMG + gidx];
    const float hv[4] = {hv4.x,hv4.y,hv4.z,hv4.w};
#pragma unroll
    for (int k=0;k<4;++k){
      float u  = sig_(uo[k]);
      float cd = th_(co[k]);
      float ns = hv[k] + u*(cd - hv[k]);          // h(1-u) + cand*u
      acc[k] = fmaf(ns, w_read[(size_t)(gidx+k)*PCNT + p], acc[k]);
    }
  }

  // ---------------- high plants: p = 64 + 8*pg + i ----------------
  // a = 2(p-64): update from (h_a, h_{a+1}); cand from (hr_a, hr_{a+1}),
  // hr_j = h_j * sigmoid(conv(sources_j; w_reset[j])) computed on ext-1 region.
  for (int i = 0; i < 8; ++i) {
    const int p = 64 + 8*pg + i;
    const int a = 2*(p-64);                       // even, 0..126
    const float* srcb = (a < 64) ? (x + (size_t)(2*a)*IMG)
                                 : (h + (size_t)(2*(a-64))*IMG);
    __syncthreads();
    stage_tile(srcb + (size_t)0*IMG, sm[0], R0, C0, tid);  // reset_a ch0
    stage_tile(srcb + (size_t)1*IMG, sm[1], R0, C0, tid);  // reset_a ch1
    stage_tile(srcb + (size_t)2*IMG, sm[2], R0, C0, tid);  // reset_{a+1} ch0
    stage_tile(srcb + (size_t)3*IMG, sm[3], R0, C0, tid);  // reset_{a+1} ch1
    stage_tile(h + (size_t)a*IMG,     sm[4], R0, C0, tid); // h_a
    stage_tile(h + (size_t)(a+1)*IMG, sm[5], R0, C0, tid); // h_{a+1}
    __syncthreads();

    { // hr tiles on ext-1 region: rows rr in [1,34], cols cc in [2,35]
      float wr0[9],wr1[9],ws0[9],ws1[9];
      load_w18(w_reset + a*18,     wr0, wr1);
      load_w18(w_reset + (a+1)*18, ws0, ws1);
      const float bra = b_reset[a], brb = b_reset[a+1];
      for (int sIdx = tid; sIdx < 34*9; sIdx += NTHREADS) {
        int row  = sIdx / 9;
        int s    = sIdx - row*9;
        int rr   = row + 1;
        int col0 = 4*s;
        int cnt  = (s==8) ? 2 : 4;
        float va[3][8], vb[3][8];
        load_rows(sm[0], rr-1, col0, va);
        load_rows(sm[1], rr-1, col0, vb);
        float ra[4] = {bra,bra,bra,bra};
        conv_acc<1>(va, wr0, ra); conv_acc<1>(vb, wr1, ra);
        load_rows(sm[2], rr-1, col0, va);
        load_rows(sm[3], rr-1, col0, vb);
        float rb[4] = {brb,brb,brb,brb};
        conv_acc<1>(va, ws0, rb); conv_acc<1>(vb, ws1, rb);
        for (int k=0;k<cnt;++k){
          int o = rr*PITCH + col0 + 2 + k;
          sm[6][o] = sm[4][o] * sig_(ra[k]);
          sm[7][o] = sm[5][o] * sig_(rb[k]);
        }
      }
    }
    __syncthreads();

    float wu0[9],wu1[9],wo0[9],wo1[9];
    load_w18(w_update + p*18, wu0, wu1);
    load_w18(w_out    + p*18, wo0, wo1);
    const float bu = b_update[p], bo = b_out[p];

    float v0[3][8], v1[3][8];
    load_rows(sm[4], trow+1, tcol, v0);
    load_rows(sm[5], trow+1, tcol, v1);
    float uo[4] = {bu,bu,bu,bu};
    conv_acc<2>(v0, wu0, uo); conv_acc<2>(v1, wu1, uo);
    load_rows(sm[6], trow+1, tcol, v0);
    load_rows(sm[7], trow+1, tcol, v1);
    float co[4] = {bo,bo,bo,bo};
    conv_acc<2>(v0, wo0, co); conv_acc<2>(v1, wo1, co);

    const float4 hv4 = *(const float4*)&h[(size_t)p*IMG + gidx];
    const float hv[4] = {hv4.x,hv4.y,hv4.z,hv4.w};
#pragma unroll
    for (int k=0;k<4;++k){
      float u  = sig_(uo[k]);
      float cd = th_(co[k]);
      float ns = hv[k] + u*(cd - hv[k]);
      acc[k] = fmaf(ns, w_read[(size_t)(gidx+k)*PCNT + p], acc[k]);
    }
  }

#pragma unroll
  for (int k=0;k<4;++k) atomicAdd(&out[gidx+k], acc[k]);
}

extern "C" void kernel_launch(void* const* d_in, const int* in_sizes, int n_in,
                              void* d_out, int out_size, void* d_ws, size_t ws_size,
                              hipStream_t stream) {
  const float* x     = (const float*)d_in[0];
  const float* h     = (const float*)d_in[1];
  const float* wrst  = (const float*)d_in[2];
  const float* brst  = (const float*)d_in[3];
  const float* wupd  = (const float*)d_in[4];
  const float* bupd  = (const float*)d_in[5];
  const float* wout  = (const float*)d_in[6];
  const float* bout  = (const float*)d_in[7];
  const float* wread = (const float*)d_in[8];
  const float* bias  = (const float*)d_in[9];
  float* out = (float*)d_out;

  hipLaunchKernelGGL(init_out, dim3(IMG/NTHREADS), dim3(NTHREADS), 0, stream, bias, out);
  hipLaunchKernelGGL(gru_fused, dim3(64*8), dim3(NTHREADS), 0, stream,
                     x, h, wrst, brst, wupd, bupd, wout, bout, wread, out);
}

// Round 2
// 177.540 us; speedup vs baseline: 1.6468x; 1.6468x over previous
//
#include <hip/hip_runtime.h>

#define PCNT 128
#define RCdim 256
#define IMG (RCdim*RCdim)
#define PITCH 40        // tile pitch in floats (160B)
#define TROWS 36        // 32 + 2*ext2
#define TELEMS (TROWS*PITCH)   // 1440 floats
#define NSLOT 360              // float4 slots per plane
#define NTHREADS 256

__device__ __forceinline__ float sig_(float x){ return 1.0f/(1.0f+__expf(-x)); }
__device__ __forceinline__ float th_(float x){ float e=__expf(2.0f*x); return 1.0f-2.0f/(e+1.0f); }

// Stage one 36x40 plane tile, origin (R0-2, C0-4), zero-padded OOB.
// 16B-aligned float4 loads: gc = C0-4+4q is mult of 4; OOB is always a full float4.
__device__ __forceinline__ void stage4(const float* __restrict__ src, float* __restrict__ dst,
                                       int R0, int C0, int tid){
#pragma unroll
  for (int j=0;j<2;++j){
    int s = j*NTHREADS + tid;
    if (s < NSLOT){
      int rr = s/10, q = s - rr*10;
      int gr = R0-2+rr, gc = C0-4+4*q;
      float4 v = make_float4(0.f,0.f,0.f,0.f);
      if ((unsigned)gr < 256u && (unsigned)gc < 253u)
        v = *(const float4*)(src + gr*RCdim + gc);
      *(float4*)(dst + 4*s) = v;
    }
  }
}

// 8-col window via 4x ds_read_b64 (col0 must be even), rows row0..row0+2
__device__ __forceinline__ void load8(const float* __restrict__ T, int row0, int col0, float v[3][8]){
#pragma unroll
  for (int dy=0;dy<3;++dy){
    const float2* p = (const float2*)&T[(row0+dy)*PITCH + col0];
    float2 a=p[0],b=p[1],c=p[2],d=p[3];
    v[dy][0]=a.x; v[dy][1]=a.y; v[dy][2]=b.x; v[dy][3]=b.y;
    v[dy][4]=c.x; v[dy][5]=c.y; v[dy][6]=d.x; v[dy][7]=d.y;
  }
}

// 8-col window via 2x ds_read_b128 (col0 mult of 4)
__device__ __forceinline__ void load8q(const float* __restrict__ T, int row0, int col0, float v[3][8]){
#pragma unroll
  for (int dy=0;dy<3;++dy){
    const float4* p = (const float4*)&T[(row0+dy)*PITCH + col0];
    float4 A=p[0], B=p[1];
    v[dy][0]=A.x; v[dy][1]=A.y; v[dy][2]=A.z; v[dy][3]=A.w;
    v[dy][4]=B.x; v[dy][5]=B.y; v[dy][6]=B.z; v[dy][7]=B.w;
  }
}

// 3x3 cross-correlation, 1x4 strip; center col in v = OFF+k+1
template<int OFF>
__device__ __forceinline__ void conv_acc(const float v[3][8], const float w9[9], float o[4]){
#pragma unroll
  for (int ky=0; ky<3; ++ky)
#pragma unroll
    for (int kx=0; kx<3; ++kx){
      const float w = w9[ky*3+kx];
#pragma unroll
      for (int k=0;k<4;++k) o[k] = fmaf(w, v[ky][k+kx+OFF], o[k]);
    }
}

__device__ __forceinline__ void load_w18(const float* __restrict__ g, float w0[9], float w1[9]){
#pragma unroll
  for (int i=0;i<9;++i){ w0[i]=g[i]; w1[i]=g[9+i]; }
}

// Compute hr_a -> sm[6], hr_{a+1} -> sm[7] on ext-1 region (rows 1..34, cols 3..36).
// reset_a sources sm[0],sm[1]; reset_{a+1} sources sm[2],sm[3]; h in sm[4],sm[5].
__device__ __forceinline__ void hr_phase(float (*sm)[TELEMS],
                                         const float* __restrict__ w_reset,
                                         const float* __restrict__ b_reset,
                                         int a, int tid){
  float wr0[9],wr1[9],ws0[9],ws1[9];
  load_w18(w_reset + a*18,     wr0, wr1);
  load_w18(w_reset + (a+1)*18, ws0, ws1);
  const float bra = b_reset[a], brb = b_reset[a+1];
  for (int sIdx = tid; sIdx < 34*9; sIdx += NTHREADS){
    int row  = sIdx/9;
    int s    = sIdx - row*9;
    int rr   = row + 1;          // 1..34
    int col0 = 4*s;              // 0..32
    float va[3][8], vb[3][8];
    load8q(sm[0], rr-1, col0, va);
    load8q(sm[1], rr-1, col0, vb);
    float ra[4] = {bra,bra,bra,bra};
    conv_acc<2>(va, wr0, ra); conv_acc<2>(vb, wr1, ra);
    load8q(sm[2], rr-1, col0, va);
    load8q(sm[3], rr-1, col0, vb);
    float rb[4] = {brb,brb,brb,brb};
    conv_acc<2>(va, ws0, rb); conv_acc<2>(vb, ws1, rb);
    int cnt = (s==8) ? 2 : 4;    // centers cc = 4s+3+k, need cc in [3,36]
    for (int k=0;k<cnt;++k){
      int o = rr*PITCH + col0 + 3 + k;
      sm[6][o] = sm[4][o] * sig_(ra[k]);
      sm[7][o] = sm[5][o] * sig_(rb[k]);
    }
  }
}

extern "C" __global__ void init_out(const float* __restrict__ bias, float* __restrict__ out){
  int i = blockIdx.x * NTHREADS + threadIdx.x;
  out[i] = bias[i];
}

extern "C" __global__ void __launch_bounds__(NTHREADS, 2)
gru_fused(const float* __restrict__ x, const float* __restrict__ h,
          const float* __restrict__ w_reset, const float* __restrict__ b_reset,
          const float* __restrict__ w_update, const float* __restrict__ b_update,
          const float* __restrict__ w_out, const float* __restrict__ b_out,
          const float* __restrict__ w_read, float* __restrict__ out)
{
  __shared__ float sm[8][TELEMS];  // 46080 B -> 3 blocks/CU
  const int tid  = threadIdx.x;
  const int bid  = blockIdx.x;
  const int pg   = bid & 7;
  const int tile = bid >> 3;
  const int R0 = (tile >> 3) * 32;
  const int C0 = (tile & 7) * 32;
  const int trow = tid >> 3;        // 0..31
  const int tcol = (tid & 7) * 4;   // 0..28
  const int gidx = (R0 + trow) * RCdim + C0 + tcol;

  float acc[4] = {0.f,0.f,0.f,0.f};
  float v0[3][8], v1[3][8];

  // ============ Phase A: pairs a = 8pg+2t -> low a, low a+1, high 64+4pg+t ============
#pragma unroll 1
  for (int t = 0; t < 4; ++t){
    const int a  = 8*pg + 2*t;          // even, < 64
    const int ph = 64 + 4*pg + t;       // = 64 + a/2
    __syncthreads();
    stage4(x + (size_t)(2*a  )*IMG, sm[0], R0,C0,tid);
    stage4(x + (size_t)(2*a+1)*IMG, sm[1], R0,C0,tid);
    stage4(x + (size_t)(2*a+2)*IMG, sm[2], R0,C0,tid);
    stage4(x + (size_t)(2*a+3)*IMG, sm[3], R0,C0,tid);
    stage4(h + (size_t)(a    )*IMG, sm[4], R0,C0,tid);
    stage4(h + (size_t)(a+1  )*IMG, sm[5], R0,C0,tid);
    __syncthreads();
    hr_phase(sm, w_reset, b_reset, a, tid);
    __syncthreads();

    float hc0[4], hc1[4], uH[4];
    { // high-plant update conv (channels h_a, h_{a+1}); capture h centers for lows
      float wa[9], wb[9];
      load_w18(w_update + ph*18, wa, wb);
      const float b = b_update[ph];
      float uo[4] = {b,b,b,b};
      load8(sm[4], trow+1, tcol+2, v0);
      load8(sm[5], trow+1, tcol+2, v1);
      conv_acc<1>(v0, wa, uo); conv_acc<1>(v1, wb, uo);
#pragma unroll
      for (int k=0;k<4;++k){ hc0[k]=v0[1][k+2]; hc1[k]=v1[1][k+2]; uH[k]=sig_(uo[k]); }
    }
    float ns0[4], ns1[4];
    { // low plant a (channels x_{2a}, x_{2a+1} for both update and cand)
      float wua[9],wub[9],woa[9],wob[9];
      load_w18(w_update + a*18, wua, wub);
      load_w18(w_out    + a*18, woa, wob);
      const float bu=b_update[a], bo=b_out[a];
      float uo[4]={bu,bu,bu,bu}, co[4]={bo,bo,bo,bo};
      load8(sm[0], trow+1, tcol+2, v0);
      load8(sm[1], trow+1, tcol+2, v1);
      conv_acc<1>(v0, wua, uo); conv_acc<1>(v1, wub, uo);
      conv_acc<1>(v0, woa, co); conv_acc<1>(v1, wob, co);
#pragma unroll
      for (int k=0;k<4;++k){ float u=sig_(uo[k]); ns0[k]=hc0[k]+u*(th_(co[k])-hc0[k]); }
    }
    { // low plant a+1
      float wua[9],wub[9],woa[9],wob[9];
      load_w18(w_update + (a+1)*18, wua, wub);
      load_w18(w_out    + (a+1)*18, woa, wob);
      const float bu=b_update[a+1], bo=b_out[a+1];
      float uo[4]={bu,bu,bu,bu}, co[4]={bo,bo,bo,bo};
      load8(sm[2], trow+1, tcol+2, v0);
      load8(sm[3], trow+1, tcol+2, v1);
      conv_acc<1>(v0, wua, uo); conv_acc<1>(v1, wub, uo);
      conv_acc<1>(v0, woa, co); conv_acc<1>(v1, wob, co);
#pragma unroll
      for (int k=0;k<4;++k){ float u=sig_(uo[k]); ns1[k]=hc1[k]+u*(th_(co[k])-hc1[k]); }
    }
#pragma unroll
    for (int k=0;k<4;++k){ // w_read pair (a, a+1): contiguous float2
      const float2 wv = *(const float2*)&w_read[(size_t)(gidx+k)*PCNT + a];
      acc[k] = fmaf(ns0[k], wv.x, fmaf(ns1[k], wv.y, acc[k]));
    }
    { // high-plant cand conv (channels hr_a, hr_{a+1}) + blend
      float woa[9], wob[9];
      load_w18(w_out + ph*18, woa, wob);
      const float bo = b_out[ph];
      float co[4]={bo,bo,bo,bo};
      load8(sm[6], trow+1, tcol+2, v0);
      load8(sm[7], trow+1, tcol+2, v1);
      conv_acc<1>(v0, woa, co); conv_acc<1>(v1, wob, co);
      const float4 hp4 = *(const float4*)&h[(size_t)ph*IMG + gidx];
      const float hp[4] = {hp4.x,hp4.y,hp4.z,hp4.w};
#pragma unroll
      for (int k=0;k<4;++k){
        float ns = hp[k] + uH[k]*(th_(co[k])-hp[k]);
        acc[k] = fmaf(ns, w_read[(size_t)(gidx+k)*PCNT + ph], acc[k]);
      }
    }
  }

  // ============ Phase B: a = 64+8pg+2t -> high plant 96+4pg+t ============
#pragma unroll 1
  for (int t = 0; t < 4; ++t){
    const int a    = 64 + 8*pg + 2*t;   // even, >= 64
    const int ph   = 96 + 4*pg + t;     // = 64 + a/2
    const int base = 16*pg + 4*t;       // reset sources: h_{base..base+3}
    __syncthreads();
    stage4(h + (size_t)(base  )*IMG, sm[0], R0,C0,tid);
    stage4(h + (size_t)(base+1)*IMG, sm[1], R0,C0,tid);
    stage4(h + (size_t)(base+2)*IMG, sm[2], R0,C0,tid);
    stage4(h + (size_t)(base+3)*IMG, sm[3], R0,C0,tid);
    stage4(h + (size_t)(a     )*IMG, sm[4], R0,C0,tid);
    stage4(h + (size_t)(a+1   )*IMG, sm[5], R0,C0,tid);
    __syncthreads();
    hr_phase(sm, w_reset, b_reset, a, tid);
    __syncthreads();

    float wa[9], wb[9];
    load_w18(w_update + ph*18, wa, wb);
    const float bu = b_update[ph];
    float uo[4] = {bu,bu,bu,bu};
    load8(sm[4], trow+1, tcol+2, v0);
    load8(sm[5], trow+1, tcol+2, v1);
    conv_acc<1>(v0, wa, uo); conv_acc<1>(v1, wb, uo);

    load_w18(w_out + ph*18, wa, wb);
    const float bo = b_out[ph];
    float co[4] = {bo,bo,bo,bo};
    load8(sm[6], trow+1, tcol+2, v0);
    load8(sm[7], trow+1, tcol+2, v1);
    conv_acc<1>(v0, wa, co); conv_acc<1>(v1, wb, co);

    const float4 hp4 = *(const float4*)&h[(size_t)ph*IMG + gidx];
    const float hp[4] = {hp4.x,hp4.y,hp4.z,hp4.w};
#pragma unroll
    for (int k=0;k<4;++k){
      float u  = sig_(uo[k]);
      float ns = hp[k] + u*(th_(co[k])-hp[k]);
      acc[k] = fmaf(ns, w_read[(size_t)(gidx+k)*PCNT + ph], acc[k]);
    }
  }

#pragma unroll
  for (int k=0;k<4;++k) atomicAdd(&out[gidx+k], acc[k]);
}

extern "C" void kernel_launch(void* const* d_in, const int* in_sizes, int n_in,
                              void* d_out, int out_size, void* d_ws, size_t ws_size,
                              hipStream_t stream) {
  const float* x     = (const float*)d_in[0];
  const float* h     = (const float*)d_in[1];
  const float* wrst  = (const float*)d_in[2];
  const float* brst  = (const float*)d_in[3];
  const float* wupd  = (const float*)d_in[4];
  const float* bupd  = (const float*)d_in[5];
  const float* wout  = (const float*)d_in[6];
  const float* bout  = (const float*)d_in[7];
  const float* wread = (const float*)d_in[8];
  const float* bias  = (const float*)d_in[9];
  float* out = (float*)d_out;

  hipLaunchKernelGGL(init_out, dim3(IMG/NTHREADS), dim3(NTHREADS), 0, stream, bias, out);
  hipLaunchKernelGGL(gru_fused, dim3(64*8), dim3(NTHREADS), 0, stream,
                     x, h, wrst, brst, wupd, bupd, wout, bout, wread, out);
}

// Round 3
// 156.856 us; speedup vs baseline: 1.8639x; 1.1319x over previous
//
#include <hip/hip_runtime.h>

#define PCNT 128
#define RCdim 256
#define IMG (RCdim*RCdim)
#define PITCH 40        // tile pitch in floats (160B)
#define TROWS 36        // 32 + 2*ext2
#define TELEMS (TROWS*PITCH)   // 1440 floats
#define NSLOT 360              // float4 slots per plane
#define NTHREADS 256
#define NTASK (34*9)           // hr strip tasks

__device__ __forceinline__ float sig_(float x){ return 1.0f/(1.0f+__expf(-x)); }
__device__ __forceinline__ float th_(float x){ float e=__expf(2.0f*x); return 1.0f-2.0f/(e+1.0f); }

// Stage one 36x40 plane tile, origin (R0-2, C0-4), zero-padded OOB, float4 loads.
__device__ __forceinline__ void stage4(const float* __restrict__ src, float* __restrict__ dst,
                                       int R0, int C0, int tid){
#pragma unroll
  for (int j=0;j<2;++j){
    int s = j*NTHREADS + tid;
    if (s < NSLOT){
      int rr = s/10, q = s - rr*10;
      int gr = R0-2+rr, gc = C0-4+4*q;
      float4 v = make_float4(0.f,0.f,0.f,0.f);
      if ((unsigned)gr < 256u && (unsigned)gc < 253u)
        v = *(const float4*)(src + gr*RCdim + gc);
      *(float4*)(dst + 4*s) = v;
    }
  }
}

// 8-col window via 4x ds_read_b64 (col0 even), rows row0..row0+2
__device__ __forceinline__ void load8(const float* __restrict__ T, int row0, int col0, float v[3][8]){
#pragma unroll
  for (int dy=0;dy<3;++dy){
    const float2* p = (const float2*)&T[(row0+dy)*PITCH + col0];
    float2 a=p[0],b=p[1],c=p[2],d=p[3];
    v[dy][0]=a.x; v[dy][1]=a.y; v[dy][2]=b.x; v[dy][3]=b.y;
    v[dy][4]=c.x; v[dy][5]=c.y; v[dy][6]=d.x; v[dy][7]=d.y;
  }
}

// 8-col window via 2x ds_read_b128 (col0 mult of 4)
__device__ __forceinline__ void load8q(const float* __restrict__ T, int row0, int col0, float v[3][8]){
#pragma unroll
  for (int dy=0;dy<3;++dy){
    const float4* p = (const float4*)&T[(row0+dy)*PITCH + col0];
    float4 A=p[0], B=p[1];
    v[dy][0]=A.x; v[dy][1]=A.y; v[dy][2]=A.z; v[dy][3]=A.w;
    v[dy][4]=B.x; v[dy][5]=B.y; v[dy][6]=B.z; v[dy][7]=B.w;
  }
}

// 3x3 cross-correlation, 1x4 strip; pixel k center col = OFF+k+1 in window
template<int OFF>
__device__ __forceinline__ void conv_acc(const float v[3][8], const float w9[9], float o[4]){
#pragma unroll
  for (int ky=0; ky<3; ++ky)
#pragma unroll
    for (int kx=0; kx<3; ++kx){
      const float w = w9[ky*3+kx];
#pragma unroll
      for (int k=0;k<4;++k) o[k] = fmaf(w, v[ky][k+kx+OFF], o[k]);
    }
}

__device__ __forceinline__ void load_w18(const float* __restrict__ g, float w0[9], float w1[9]){
#pragma unroll
  for (int i=0;i<9;++i){ w0[i]=g[i]; w1[i]=g[9+i]; }
}

// Reset-gate sigmoids for pair (a, a+1) into registers.
// Sources: reset_a <- sm[0],sm[1]; reset_{a+1} <- sm[2],sm[3].
__device__ __forceinline__ void hr_compute(float (*sm)[TELEMS],
    const float* __restrict__ w_reset, const float* __restrict__ b_reset,
    int a, int tid, float ga[2][4], float gb[2][4]){
  float wr0[9],wr1[9],ws0[9],ws1[9];
  load_w18(w_reset + a*18,     wr0, wr1);
  load_w18(w_reset + (a+1)*18, ws0, ws1);
  const float bra = b_reset[a], brb = b_reset[a+1];
#pragma unroll
  for (int j=0;j<2;++j){
    int sIdx = j*NTHREADS + tid;
    if (sIdx < NTASK){
      int row = sIdx/9, s = sIdx - row*9;
      int rr = row + 1, col0 = 4*s;
      float va[3][8], vb[3][8];
      load8q(sm[0], rr-1, col0, va);
      load8q(sm[1], rr-1, col0, vb);
      float ra[4] = {bra,bra,bra,bra};
      conv_acc<2>(va, wr0, ra); conv_acc<2>(vb, wr1, ra);
      load8q(sm[2], rr-1, col0, va);
      load8q(sm[3], rr-1, col0, vb);
      float rb[4] = {brb,brb,brb,brb};
      conv_acc<2>(va, ws0, rb); conv_acc<2>(vb, ws1, rb);
#pragma unroll
      for (int k=0;k<4;++k){ ga[j][k]=sig_(ra[k]); gb[j][k]=sig_(rb[k]); }
    }
  }
}

// hr_a -> sm[0] interior, hr_{a+1} -> sm[2] interior (rows 1..34, cols 3..36).
__device__ __forceinline__ void hr_write(float (*sm)[TELEMS], int tid,
    const float ga[2][4], const float gb[2][4]){
#pragma unroll
  for (int j=0;j<2;++j){
    int sIdx = j*NTHREADS + tid;
    if (sIdx < NTASK){
      int row = sIdx/9, s = sIdx - row*9;
      int rr = row + 1, col0 = 4*s;
      int cnt = (s==8) ? 2 : 4;
      for (int k=0;k<cnt;++k){
        int o = rr*PITCH + col0 + 3 + k;
        sm[0][o] = sm[4][o] * ga[j][k];
        sm[2][o] = sm[5][o] * gb[j][k];
      }
    }
  }
}

extern "C" __global__ void init_out(const float* __restrict__ bias, float* __restrict__ out){
  int i = blockIdx.x * NTHREADS + threadIdx.x;
  out[i] = bias[i];
}

extern "C" __global__ void __launch_bounds__(NTHREADS, 4)
gru_fused(const float* __restrict__ x, const float* __restrict__ h,
          const float* __restrict__ w_reset, const float* __restrict__ b_reset,
          const float* __restrict__ w_update, const float* __restrict__ b_update,
          const float* __restrict__ w_out, const float* __restrict__ b_out,
          const float* __restrict__ w_read, float* __restrict__ out)
{
  __shared__ float sm[6][TELEMS];  // 34560 B -> 4 blocks/CU
  const int tid  = threadIdx.x;
  const int bid  = blockIdx.x;
  const int pg   = bid & 15;        // 16 plant groups
  const int tile = bid >> 4;        // 0..63
  const int R0 = (tile >> 3) * 32;
  const int C0 = (tile & 7) * 32;
  const int trow = tid >> 3;        // 0..31
  const int tcol = (tid & 7) * 4;   // 0..28
  const int gidx = (R0 + trow) * RCdim + C0 + tcol;

  float acc[4] = {0.f,0.f,0.f,0.f};
  float v0[3][8], v1[3][8];

  // ==== Phase A: a = 4pg+2t -> low a, low a+1, high 64+2pg+t ====
#pragma unroll 1
  for (int t = 0; t < 2; ++t){
    const int a  = 4*pg + 2*t;        // even, < 64
    const int ph = 64 + 2*pg + t;
    __syncthreads();
    stage4(x + (size_t)(2*a  )*IMG, sm[0], R0,C0,tid);
    stage4(x + (size_t)(2*a+1)*IMG, sm[1], R0,C0,tid);
    stage4(x + (size_t)(2*a+2)*IMG, sm[2], R0,C0,tid);
    stage4(x + (size_t)(2*a+3)*IMG, sm[3], R0,C0,tid);
    stage4(h + (size_t)(a    )*IMG, sm[4], R0,C0,tid);
    stage4(h + (size_t)(a+1  )*IMG, sm[5], R0,C0,tid);
    __syncthreads();

    float hc0[4], hc1[4], uH[4];
    { // high update conv (h_a, h_{a+1}); capture h centers for lows
      float wa[9], wb[9];
      load_w18(w_update + ph*18, wa, wb);
      const float b = b_update[ph];
      float uo[4] = {b,b,b,b};
      load8(sm[4], trow+1, tcol+2, v0);
      load8(sm[5], trow+1, tcol+2, v1);
      conv_acc<1>(v0, wa, uo); conv_acc<1>(v1, wb, uo);
#pragma unroll
      for (int k=0;k<4;++k){ hc0[k]=v0[1][k+2]; hc1[k]=v1[1][k+2]; uH[k]=sig_(uo[k]); }
    }
    float ns0[4], ns1[4];
    { // low plant a
      float wua[9],wub[9],woa[9],wob[9];
      load_w18(w_update + a*18, wua, wub);
      load_w18(w_out    + a*18, woa, wob);
      const float bu=b_update[a], bo=b_out[a];
      float uo[4]={bu,bu,bu,bu}, co[4]={bo,bo,bo,bo};
      load8(sm[0], trow+1, tcol+2, v0);
      load8(sm[1], trow+1, tcol+2, v1);
      conv_acc<1>(v0, wua, uo); conv_acc<1>(v1, wub, uo);
      conv_acc<1>(v0, woa, co); conv_acc<1>(v1, wob, co);
#pragma unroll
      for (int k=0;k<4;++k){ float u=sig_(uo[k]); ns0[k]=hc0[k]+u*(th_(co[k])-hc0[k]); }
    }
    { // low plant a+1
      float wua[9],wub[9],woa[9],wob[9];
      load_w18(w_update + (a+1)*18, wua, wub);
      load_w18(w_out    + (a+1)*18, woa, wob);
      const float bu=b_update[a+1], bo=b_out[a+1];
      float uo[4]={bu,bu,bu,bu}, co[4]={bo,bo,bo,bo};
      load8(sm[2], trow+1, tcol+2, v0);
      load8(sm[3], trow+1, tcol+2, v1);
      conv_acc<1>(v0, wua, uo); conv_acc<1>(v1, wub, uo);
      conv_acc<1>(v0, woa, co); conv_acc<1>(v1, wob, co);
#pragma unroll
      for (int k=0;k<4;++k){ float u=sig_(uo[k]); ns1[k]=hc1[k]+u*(th_(co[k])-hc1[k]); }
    }
#pragma unroll
    for (int k=0;k<4;++k){
      const float2 wv = *(const float2*)&w_read[(size_t)(gidx+k)*PCNT + a];
      acc[k] = fmaf(ns0[k], wv.x, fmaf(ns1[k], wv.y, acc[k]));
    }
    float ga[2][4], gb[2][4];
    hr_compute(sm, w_reset, b_reset, a, tid, ga, gb);
    __syncthreads();                 // all reads of sm[0..3] done
    hr_write(sm, tid, ga, gb);       // hr_a -> sm[0], hr_{a+1} -> sm[2]
    __syncthreads();
    { // high cand conv (hr pair) + blend
      float woa[9], wob[9];
      load_w18(w_out + ph*18, woa, wob);
      const float bo = b_out[ph];
      float co[4]={bo,bo,bo,bo};
      load8(sm[0], trow+1, tcol+2, v0);
      load8(sm[2], trow+1, tcol+2, v1);
      conv_acc<1>(v0, woa, co); conv_acc<1>(v1, wob, co);
      const float4 hp4 = *(const float4*)&h[(size_t)ph*IMG + gidx];
      const float hp[4] = {hp4.x,hp4.y,hp4.z,hp4.w};
#pragma unroll
      for (int k=0;k<4;++k){
        float ns = hp[k] + uH[k]*(th_(co[k])-hp[k]);
        acc[k] = fmaf(ns, w_read[(size_t)(gidx+k)*PCNT + ph], acc[k]);
      }
    }
  }

  // ==== Phase B: a = 64+4pg+2t -> high plant 96+2pg+t ====
#pragma unroll 1
  for (int t = 0; t < 2; ++t){
    const int a    = 64 + 4*pg + 2*t;
    const int ph   = 96 + 2*pg + t;
    const int base = 8*pg + 4*t;      // reset sources h_{base..base+3}
    __syncthreads();
    stage4(h + (size_t)(base  )*IMG, sm[0], R0,C0,tid);
    stage4(h + (size_t)(base+1)*IMG, sm[1], R0,C0,tid);
    stage4(h + (size_t)(base+2)*IMG, sm[2], R0,C0,tid);
    stage4(h + (size_t)(base+3)*IMG, sm[3], R0,C0,tid);
    stage4(h + (size_t)(a     )*IMG, sm[4], R0,C0,tid);
    stage4(h + (size_t)(a+1   )*IMG, sm[5], R0,C0,tid);
    __syncthreads();

    float uH[4];
    { // update conv (h_a, h_{a+1})
      float wa[9], wb[9];
      load_w18(w_update + ph*18, wa, wb);
      const float bu = b_update[ph];
      float uo[4] = {bu,bu,bu,bu};
      load8(sm[4], trow+1, tcol+2, v0);
      load8(sm[5], trow+1, tcol+2, v1);
      conv_acc<1>(v0, wa, uo); conv_acc<1>(v1, wb, uo);
#pragma unroll
      for (int k=0;k<4;++k) uH[k]=sig_(uo[k]);
    }
    float ga[2][4], gb[2][4];
    hr_compute(sm, w_reset, b_reset, a, tid, ga, gb);
    __syncthreads();
    hr_write(sm, tid, ga, gb);
    __syncthreads();
    { // cand conv (hr pair) + blend
      float wa[9], wb[9];
      load_w18(w_out + ph*18, wa, wb);
      const float bo = b_out[ph];
      float co[4] = {bo,bo,bo,bo};
      load8(sm[0], trow+1, tcol+2, v0);
      load8(sm[2], trow+1, tcol+2, v1);
      conv_acc<1>(v0, wa, co); conv_acc<1>(v1, wb, co);
      const float4 hp4 = *(const float4*)&h[(size_t)ph*IMG + gidx];
      const float hp[4] = {hp4.x,hp4.y,hp4.z,hp4.w};
#pragma unroll
      for (int k=0;k<4;++k){
        float u  = uH[k];
        float ns = hp[k] + u*(th_(co[k])-hp[k]);
        acc[k] = fmaf(ns, w_read[(size_t)(gidx+k)*PCNT + ph], acc[k]);
      }
    }
  }

#pragma unroll
  for (int k=0;k<4;++k) atomicAdd(&out[gidx+k], acc[k]);
}

extern "C" void kernel_launch(void* const* d_in, const int* in_sizes, int n_in,
                              void* d_out, int out_size, void* d_ws, size_t ws_size,
                              hipStream_t stream) {
  const float* x     = (const float*)d_in[0];
  const float* h     = (const float*)d_in[1];
  const float* wrst  = (const float*)d_in[2];
  const float* brst  = (const float*)d_in[3];
  const float* wupd  = (const float*)d_in[4];
  const float* bupd  = (const float*)d_in[5];
  const float* wout  = (const float*)d_in[6];
  const float* bout  = (const float*)d_in[7];
  const float* wread = (const float*)d_in[8];
  const float* bias  = (const float*)d_in[9];
  float* out = (float*)d_out;

  hipLaunchKernelGGL(init_out, dim3(IMG/NTHREADS), dim3(NTHREADS), 0, stream, bias, out);
  hipLaunchKernelGGL(gru_fused, dim3(64*16), dim3(NTHREADS), 0, stream,
                     x, h, wrst, brst, wupd, bupd, wout, bout, wread, out);
}

// Round 4
// 80.625 us; speedup vs baseline: 3.6263x; 1.9455x over previous
//
#include <hip/hip_runtime.h>

#define PCNT 128
#define RCdim 256
#define IMG (RCdim*RCdim)
#define PITCH 40        // tile pitch in floats (160B)
#define TROWS 36        // 32 + 2*ext2
#define TELEMS (TROWS*PITCH)   // 1440 floats
#define NSLOT 360              // float4 slots per plane
#define NTHREADS 256
#define NTASK (34*9)           // hr strip tasks

__device__ __forceinline__ float sig_(float x){ return 1.0f/(1.0f+__expf(-x)); }
__device__ __forceinline__ float th_(float x){ float e=__expf(2.0f*x); return 1.0f-2.0f/(e+1.0f); }

// Stage one 36x40 plane tile, origin (R0-2, C0-4), zero-padded OOB, float4 loads.
__device__ __forceinline__ void stage4(const float* __restrict__ src, float* __restrict__ dst,
                                       int R0, int C0, int tid){
#pragma unroll
  for (int j=0;j<2;++j){
    int s = j*NTHREADS + tid;
    if (s < NSLOT){
      int rr = s/10, q = s - rr*10;
      int gr = R0-2+rr, gc = C0-4+4*q;
      float4 v = make_float4(0.f,0.f,0.f,0.f);
      if ((unsigned)gr < 256u && (unsigned)gc < 253u)
        v = *(const float4*)(src + gr*RCdim + gc);
      *(float4*)(dst + 4*s) = v;
    }
  }
}

// 8-col window via 4x ds_read_b64 (col0 even), rows row0..row0+2
__device__ __forceinline__ void load8(const float* __restrict__ T, int row0, int col0, float v[3][8]){
#pragma unroll
  for (int dy=0;dy<3;++dy){
    const float2* p = (const float2*)&T[(row0+dy)*PITCH + col0];
    float2 a=p[0],b=p[1],c=p[2],d=p[3];
    v[dy][0]=a.x; v[dy][1]=a.y; v[dy][2]=b.x; v[dy][3]=b.y;
    v[dy][4]=c.x; v[dy][5]=c.y; v[dy][6]=d.x; v[dy][7]=d.y;
  }
}

// 8-col window via 2x ds_read_b128 (col0 mult of 4)
__device__ __forceinline__ void load8q(const float* __restrict__ T, int row0, int col0, float v[3][8]){
#pragma unroll
  for (int dy=0;dy<3;++dy){
    const float4* p = (const float4*)&T[(row0+dy)*PITCH + col0];
    float4 A=p[0], B=p[1];
    v[dy][0]=A.x; v[dy][1]=A.y; v[dy][2]=A.z; v[dy][3]=A.w;
    v[dy][4]=B.x; v[dy][5]=B.y; v[dy][6]=B.z; v[dy][7]=B.w;
  }
}

// 3x3 cross-correlation, 1x4 strip; pixel k center col = OFF+k+1 in window
template<int OFF>
__device__ __forceinline__ void conv_acc(const float v[3][8], const float w9[9], float o[4]){
#pragma unroll
  for (int ky=0; ky<3; ++ky)
#pragma unroll
    for (int kx=0; kx<3; ++kx){
      const float w = w9[ky*3+kx];
#pragma unroll
      for (int k=0;k<4;++k) o[k] = fmaf(w, v[ky][k+kx+OFF], o[k]);
    }
}

__device__ __forceinline__ void load_w18(const float* __restrict__ g, float w0[9], float w1[9]){
#pragma unroll
  for (int i=0;i<9;++i){ w0[i]=g[i]; w1[i]=g[9+i]; }
}

// Reset-gate sigmoids for pair (a, a+1) into registers.
__device__ __forceinline__ void hr_compute(float (*sm)[TELEMS],
    const float* __restrict__ w_reset, const float* __restrict__ b_reset,
    int a, int tid, float ga[2][4], float gb[2][4]){
  float wr0[9],wr1[9],ws0[9],ws1[9];
  load_w18(w_reset + a*18,     wr0, wr1);
  load_w18(w_reset + (a+1)*18, ws0, ws1);
  const float bra = b_reset[a], brb = b_reset[a+1];
#pragma unroll
  for (int j=0;j<2;++j){
    int sIdx = j*NTHREADS + tid;
    if (sIdx < NTASK){
      int row = sIdx/9, s = sIdx - row*9;
      int rr = row + 1, col0 = 4*s;
      float va[3][8], vb[3][8];
      load8q(sm[0], rr-1, col0, va);
      load8q(sm[1], rr-1, col0, vb);
      float ra[4] = {bra,bra,bra,bra};
      conv_acc<2>(va, wr0, ra); conv_acc<2>(vb, wr1, ra);
      load8q(sm[2], rr-1, col0, va);
      load8q(sm[3], rr-1, col0, vb);
      float rb[4] = {brb,brb,brb,brb};
      conv_acc<2>(va, ws0, rb); conv_acc<2>(vb, ws1, rb);
#pragma unroll
      for (int k=0;k<4;++k){ ga[j][k]=sig_(ra[k]); gb[j][k]=sig_(rb[k]); }
    }
  }
}

// hr_a -> sm[0] interior, hr_{a+1} -> sm[2] interior (rows 1..34, cols 3..36).
__device__ __forceinline__ void hr_write(float (*sm)[TELEMS], int tid,
    const float ga[2][4], const float gb[2][4]){
#pragma unroll
  for (int j=0;j<2;++j){
    int sIdx = j*NTHREADS + tid;
    if (sIdx < NTASK){
      int row = sIdx/9, s = sIdx - row*9;
      int rr = row + 1, col0 = 4*s;
      int cnt = (s==8) ? 2 : 4;
      for (int k=0;k<cnt;++k){
        int o = rr*PITCH + col0 + 3 + k;
        sm[0][o] = sm[4][o] * ga[j][k];
        sm[2][o] = sm[5][o] * gb[j][k];
      }
    }
  }
}

__global__ void init_out(const float* __restrict__ bias, float* __restrict__ out){
  int i = blockIdx.x * NTHREADS + threadIdx.x;
  out[i] = bias[i];
}

// out[px] = bias[px] + sum_p ns[p][px] * w_read[px][p]
__global__ void __launch_bounds__(NTHREADS)
reduce_out(const float* __restrict__ ns, const float* __restrict__ w_read,
           const float* __restrict__ bias, float* __restrict__ out){
  const int px = blockIdx.x * NTHREADS + threadIdx.x;
  float acc = bias[px];
  const float* wr = w_read + (size_t)px * PCNT;
#pragma unroll 4
  for (int p0 = 0; p0 < PCNT; p0 += 4){
    const float4 w4 = *(const float4*)&wr[p0];
    acc = fmaf(ns[(size_t)(p0  )*IMG + px], w4.x,
          fmaf(ns[(size_t)(p0+1)*IMG + px], w4.y,
          fmaf(ns[(size_t)(p0+2)*IMG + px], w4.z,
          fmaf(ns[(size_t)(p0+3)*IMG + px], w4.w, acc))));
  }
  out[px] = acc;
}

template<bool SPLIT>
__global__ void __launch_bounds__(NTHREADS, 4)
gru_fused(const float* __restrict__ x, const float* __restrict__ h,
          const float* __restrict__ w_reset, const float* __restrict__ b_reset,
          const float* __restrict__ w_update, const float* __restrict__ b_update,
          const float* __restrict__ w_out, const float* __restrict__ b_out,
          const float* __restrict__ w_read, float* __restrict__ ws,
          float* __restrict__ out)
{
  __shared__ float sm[6][TELEMS];  // 34560 B -> 4 blocks/CU
  const int tid  = threadIdx.x;
  const int bid  = blockIdx.x;
  const int pg   = bid & 15;
  const int tile = bid >> 4;
  const int R0 = (tile >> 3) * 32;
  const int C0 = (tile & 7) * 32;
  const int trow = tid >> 3;
  const int tcol = (tid & 7) * 4;
  const int gidx = (R0 + trow) * RCdim + C0 + tcol;

  float acc[4] = {0.f,0.f,0.f,0.f};
  float v0[3][8], v1[3][8];

  // ==== Phase A: a = 4pg+2t -> low a, low a+1, high 64+2pg+t ====
#pragma unroll 1
  for (int t = 0; t < 2; ++t){
    const int a  = 4*pg + 2*t;
    const int ph = 64 + 2*pg + t;
    __syncthreads();
    stage4(x + (size_t)(2*a  )*IMG, sm[0], R0,C0,tid);
    stage4(x + (size_t)(2*a+1)*IMG, sm[1], R0,C0,tid);
    stage4(x + (size_t)(2*a+2)*IMG, sm[2], R0,C0,tid);
    stage4(x + (size_t)(2*a+3)*IMG, sm[3], R0,C0,tid);
    stage4(h + (size_t)(a    )*IMG, sm[4], R0,C0,tid);
    stage4(h + (size_t)(a+1  )*IMG, sm[5], R0,C0,tid);
    __syncthreads();

    float hc0[4], hc1[4], uH[4];
    { // high update conv (h_a, h_{a+1}); capture h centers for lows
      float wa[9], wb[9];
      load_w18(w_update + ph*18, wa, wb);
      const float b = b_update[ph];
      float uo[4] = {b,b,b,b};
      load8(sm[4], trow+1, tcol+2, v0);
      load8(sm[5], trow+1, tcol+2, v1);
      conv_acc<1>(v0, wa, uo); conv_acc<1>(v1, wb, uo);
#pragma unroll
      for (int k=0;k<4;++k){ hc0[k]=v0[1][k+2]; hc1[k]=v1[1][k+2]; uH[k]=sig_(uo[k]); }
    }
    float ns0[4], ns1[4];
    { // low plant a
      float wua[9],wub[9],woa[9],wob[9];
      load_w18(w_update + a*18, wua, wub);
      load_w18(w_out    + a*18, woa, wob);
      const float bu=b_update[a], bo=b_out[a];
      float uo[4]={bu,bu,bu,bu}, co[4]={bo,bo,bo,bo};
      load8(sm[0], trow+1, tcol+2, v0);
      load8(sm[1], trow+1, tcol+2, v1);
      conv_acc<1>(v0, wua, uo); conv_acc<1>(v1, wub, uo);
      conv_acc<1>(v0, woa, co); conv_acc<1>(v1, wob, co);
#pragma unroll
      for (int k=0;k<4;++k){ float u=sig_(uo[k]); ns0[k]=hc0[k]+u*(th_(co[k])-hc0[k]); }
    }
    { // low plant a+1
      float wua[9],wub[9],woa[9],wob[9];
      load_w18(w_update + (a+1)*18, wua, wub);
      load_w18(w_out    + (a+1)*18, woa, wob);
      const float bu=b_update[a+1], bo=b_out[a+1];
      float uo[4]={bu,bu,bu,bu}, co[4]={bo,bo,bo,bo};
      load8(sm[2], trow+1, tcol+2, v0);
      load8(sm[3], trow+1, tcol+2, v1);
      conv_acc<1>(v0, wua, uo); conv_acc<1>(v1, wub, uo);
      conv_acc<1>(v0, woa, co); conv_acc<1>(v1, wob, co);
#pragma unroll
      for (int k=0;k<4;++k){ float u=sig_(uo[k]); ns1[k]=hc1[k]+u*(th_(co[k])-hc1[k]); }
    }
    if (SPLIT){
      *(float4*)&ws[(size_t)a    *IMG + gidx] = make_float4(ns0[0],ns0[1],ns0[2],ns0[3]);
      *(float4*)&ws[(size_t)(a+1)*IMG + gidx] = make_float4(ns1[0],ns1[1],ns1[2],ns1[3]);
    } else {
#pragma unroll
      for (int k=0;k<4;++k){
        const float2 wv = *(const float2*)&w_read[(size_t)(gidx+k)*PCNT + a];
        acc[k] = fmaf(ns0[k], wv.x, fmaf(ns1[k], wv.y, acc[k]));
      }
    }
    float ga[2][4], gb[2][4];
    hr_compute(sm, w_reset, b_reset, a, tid, ga, gb);
    __syncthreads();
    hr_write(sm, tid, ga, gb);
    __syncthreads();
    { // high cand conv (hr pair) + blend
      float woa[9], wob[9];
      load_w18(w_out + ph*18, woa, wob);
      const float bo = b_out[ph];
      float co[4]={bo,bo,bo,bo};
      load8(sm[0], trow+1, tcol+2, v0);
      load8(sm[2], trow+1, tcol+2, v1);
      conv_acc<1>(v0, woa, co); conv_acc<1>(v1, wob, co);
      const float4 hp4 = *(const float4*)&h[(size_t)ph*IMG + gidx];
      const float hp[4] = {hp4.x,hp4.y,hp4.z,hp4.w};
      float nsH[4];
#pragma unroll
      for (int k=0;k<4;++k) nsH[k] = hp[k] + uH[k]*(th_(co[k])-hp[k]);
      if (SPLIT){
        *(float4*)&ws[(size_t)ph*IMG + gidx] = make_float4(nsH[0],nsH[1],nsH[2],nsH[3]);
      } else {
#pragma unroll
        for (int k=0;k<4;++k)
          acc[k] = fmaf(nsH[k], w_read[(size_t)(gidx+k)*PCNT + ph], acc[k]);
      }
    }
  }

  // ==== Phase B: a = 64+4pg+2t -> high plant 96+2pg+t ====
#pragma unroll 1
  for (int t = 0; t < 2; ++t){
    const int a    = 64 + 4*pg + 2*t;
    const int ph   = 96 + 2*pg + t;
    const int base = 8*pg + 4*t;
    __syncthreads();
    stage4(h + (size_t)(base  )*IMG, sm[0], R0,C0,tid);
    stage4(h + (size_t)(base+1)*IMG, sm[1], R0,C0,tid);
    stage4(h + (size_t)(base+2)*IMG, sm[2], R0,C0,tid);
    stage4(h + (size_t)(base+3)*IMG, sm[3], R0,C0,tid);
    stage4(h + (size_t)(a     )*IMG, sm[4], R0,C0,tid);
    stage4(h + (size_t)(a+1   )*IMG, sm[5], R0,C0,tid);
    __syncthreads();

    float uH[4];
    {
      float wa[9], wb[9];
      load_w18(w_update + ph*18, wa, wb);
      const float bu = b_update[ph];
      float uo[4] = {bu,bu,bu,bu};
      load8(sm[4], trow+1, tcol+2, v0);
      load8(sm[5], trow+1, tcol+2, v1);
      conv_acc<1>(v0, wa, uo); conv_acc<1>(v1, wb, uo);
#pragma unroll
      for (int k=0;k<4;++k) uH[k]=sig_(uo[k]);
    }
    float ga[2][4], gb[2][4];
    hr_compute(sm, w_reset, b_reset, a, tid, ga, gb);
    __syncthreads();
    hr_write(sm, tid, ga, gb);
    __syncthreads();
    {
      float wa[9], wb[9];
      load_w18(w_out + ph*18, wa, wb);
      const float bo = b_out[ph];
      float co[4] = {bo,bo,bo,bo};
      load8(sm[0], trow+1, tcol+2, v0);
      load8(sm[2], trow+1, tcol+2, v1);
      conv_acc<1>(v0, wa, co); conv_acc<1>(v1, wb, co);
      const float4 hp4 = *(const float4*)&h[(size_t)ph*IMG + gidx];
      const float hp[4] = {hp4.x,hp4.y,hp4.z,hp4.w};
      float nsH[4];
#pragma unroll
      for (int k=0;k<4;++k) nsH[k] = hp[k] + uH[k]*(th_(co[k])-hp[k]);
      if (SPLIT){
        *(float4*)&ws[(size_t)ph*IMG + gidx] = make_float4(nsH[0],nsH[1],nsH[2],nsH[3]);
      } else {
#pragma unroll
        for (int k=0;k<4;++k)
          acc[k] = fmaf(nsH[k], w_read[(size_t)(gidx+k)*PCNT + ph], acc[k]);
      }
    }
  }

  if (!SPLIT){
#pragma unroll
    for (int k=0;k<4;++k) atomicAdd(&out[gidx+k], acc[k]);
  }
}

extern "C" void kernel_launch(void* const* d_in, const int* in_sizes, int n_in,
                              void* d_out, int out_size, void* d_ws, size_t ws_size,
                              hipStream_t stream) {
  const float* x     = (const float*)d_in[0];
  const float* h     = (const float*)d_in[1];
  const float* wrst  = (const float*)d_in[2];
  const float* brst  = (const float*)d_in[3];
  const float* wupd  = (const float*)d_in[4];
  const float* bupd  = (const float*)d_in[5];
  const float* wout  = (const float*)d_in[6];
  const float* bout  = (const float*)d_in[7];
  const float* wread = (const float*)d_in[8];
  const float* bias  = (const float*)d_in[9];
  float* out = (float*)d_out;
  float* ws  = (float*)d_ws;

  const bool split = ws_size >= (size_t)PCNT * IMG * sizeof(float);
  if (split){
    hipLaunchKernelGGL(gru_fused<true>, dim3(64*16), dim3(NTHREADS), 0, stream,
                       x, h, wrst, brst, wupd, bupd, wout, bout, wread, ws, out);
    hipLaunchKernelGGL(reduce_out, dim3(IMG/NTHREADS), dim3(NTHREADS), 0, stream,
                       ws, wread, bias, out);
  } else {
    hipLaunchKernelGGL(init_out, dim3(IMG/NTHREADS), dim3(NTHREADS), 0, stream, bias, out);
    hipLaunchKernelGGL(gru_fused<false>, dim3(64*16), dim3(NTHREADS), 0, stream,
                       x, h, wrst, brst, wupd, bupd, wout, bout, wread, ws, out);
  }
}

// Round 5
// 66.679 us; speedup vs baseline: 4.3847x; 1.2091x over previous
//
#include <hip/hip_runtime.h>

#define PCNT 128
#define RCdim 256
#define IMG (RCdim*RCdim)
#define PITCH 42        // tile pitch in floats; 42 mod 4 = 2 -> rows alternate bank class (conflict fix)
#define TROWS 36        // 32 + 2*ext2
#define TELEMS (TROWS*PITCH)   // 1512 floats
#define NSLOT 360              // float4 load slots per plane (10 per row)
#define NTHREADS 256
#define NTASK (34*9)           // hr strip tasks

__device__ __forceinline__ float sig_(float x){ return 1.0f/(1.0f+__expf(-x)); }
__device__ __forceinline__ float th_(float x){ float e=__expf(2.0f*x); return 1.0f-2.0f/(e+1.0f); }

// Stage one 36x40 plane tile (pitch 42), origin (R0-2, C0-4), zero-padded OOB.
// Global: float4 coalesced. LDS: 2x ds_write_b64 (pitch 42 breaks 16B align).
__device__ __forceinline__ void stage4(const float* __restrict__ src, float* __restrict__ dst,
                                       int R0, int C0, int tid){
#pragma unroll
  for (int j=0;j<2;++j){
    int s = j*NTHREADS + tid;
    if (s < NSLOT){
      int rr = s/10, q = s - rr*10;
      int gr = R0-2+rr, gc = C0-4+4*q;
      float4 v = make_float4(0.f,0.f,0.f,0.f);
      if ((unsigned)gr < 256u && (unsigned)gc < 253u)
        v = *(const float4*)(src + gr*RCdim + gc);
      float* d = dst + rr*PITCH + 4*q;
      *(float2*)(d  ) = make_float2(v.x, v.y);
      *(float2*)(d+2) = make_float2(v.z, v.w);
    }
  }
}

// 8-col window via 4x ds_read_b64 (col0 even), rows row0..row0+2
__device__ __forceinline__ void load8(const float* __restrict__ T, int row0, int col0, float v[3][8]){
#pragma unroll
  for (int dy=0;dy<3;++dy){
    const float2* p = (const float2*)&T[(row0+dy)*PITCH + col0];
    float2 a=p[0],b=p[1],c=p[2],d=p[3];
    v[dy][0]=a.x; v[dy][1]=a.y; v[dy][2]=b.x; v[dy][3]=b.y;
    v[dy][4]=c.x; v[dy][5]=c.y; v[dy][6]=d.x; v[dy][7]=d.y;
  }
}

// 3x3 cross-correlation, 1x4 strip; pixel k center col = OFF+k+1 in window
template<int OFF>
__device__ __forceinline__ void conv_acc(const float v[3][8], const float w9[9], float o[4]){
#pragma unroll
  for (int ky=0; ky<3; ++ky)
#pragma unroll
    for (int kx=0; kx<3; ++kx){
      const float w = w9[ky*3+kx];
#pragma unroll
      for (int k=0;k<4;++k) o[k] = fmaf(w, v[ky][k+kx+OFF], o[k]);
    }
}

__device__ __forceinline__ void load_w18(const float* __restrict__ g, float w0[9], float w1[9]){
#pragma unroll
  for (int i=0;i<9;++i){ w0[i]=g[i]; w1[i]=g[9+i]; }
}

// Reset-gate sigmoids for pair (a, a+1) into registers.
__device__ __forceinline__ void hr_compute(float (*sm)[TELEMS],
    const float* __restrict__ w_reset, const float* __restrict__ b_reset,
    int a, int tid, float ga[2][4], float gb[2][4]){
  float wr0[9],wr1[9],ws0[9],ws1[9];
  load_w18(w_reset + a*18,     wr0, wr1);
  load_w18(w_reset + (a+1)*18, ws0, ws1);
  const float bra = b_reset[a], brb = b_reset[a+1];
#pragma unroll
  for (int j=0;j<2;++j){
    int sIdx = j*NTHREADS + tid;
    if (sIdx < NTASK){
      int row = sIdx/9, s = sIdx - row*9;
      int rr = row + 1, col0 = 4*s;
      float va[3][8], vb[3][8];
      load8(sm[0], rr-1, col0, va);
      load8(sm[1], rr-1, col0, vb);
      float ra[4] = {bra,bra,bra,bra};
      conv_acc<2>(va, wr0, ra); conv_acc<2>(vb, wr1, ra);
      load8(sm[2], rr-1, col0, va);
      load8(sm[3], rr-1, col0, vb);
      float rb[4] = {brb,brb,brb,brb};
      conv_acc<2>(va, ws0, rb); conv_acc<2>(vb, ws1, rb);
#pragma unroll
      for (int k=0;k<4;++k){ ga[j][k]=sig_(ra[k]); gb[j][k]=sig_(rb[k]); }
    }
  }
}

// hr_a -> sm[0] interior, hr_{a+1} -> sm[2] interior (rows 1..34, cols 3..36).
__device__ __forceinline__ void hr_write(float (*sm)[TELEMS], int tid,
    const float ga[2][4], const float gb[2][4]){
#pragma unroll
  for (int j=0;j<2;++j){
    int sIdx = j*NTHREADS + tid;
    if (sIdx < NTASK){
      int row = sIdx/9, s = sIdx - row*9;
      int rr = row + 1, col0 = 4*s;
      int cnt = (s==8) ? 2 : 4;
      for (int k=0;k<cnt;++k){
        int o = rr*PITCH + col0 + 3 + k;
        sm[0][o] = sm[4][o] * ga[j][k];
        sm[2][o] = sm[5][o] * gb[j][k];
      }
    }
  }
}

__global__ void init_out(const float* __restrict__ bias, float* __restrict__ out){
  int i = blockIdx.x * NTHREADS + threadIdx.x;
  out[i] = bias[i];
}

// out[px] = bias[px] + sum_p ns[p][px] * w_read[px][p]
__global__ void __launch_bounds__(NTHREADS)
reduce_out(const float* __restrict__ ns, const float* __restrict__ w_read,
           const float* __restrict__ bias, float* __restrict__ out){
  const int px = blockIdx.x * NTHREADS + threadIdx.x;
  float acc = bias[px];
  const float* wr = w_read + (size_t)px * PCNT;
#pragma unroll 4
  for (int p0 = 0; p0 < PCNT; p0 += 4){
    const float4 w4 = *(const float4*)&wr[p0];
    acc = fmaf(ns[(size_t)(p0  )*IMG + px], w4.x,
          fmaf(ns[(size_t)(p0+1)*IMG + px], w4.y,
          fmaf(ns[(size_t)(p0+2)*IMG + px], w4.z,
          fmaf(ns[(size_t)(p0+3)*IMG + px], w4.w, acc))));
  }
  out[px] = acc;
}

template<bool SPLIT>
__global__ void __launch_bounds__(NTHREADS, 4)
gru_fused(const float* __restrict__ x, const float* __restrict__ h,
          const float* __restrict__ w_reset, const float* __restrict__ b_reset,
          const float* __restrict__ w_update, const float* __restrict__ b_update,
          const float* __restrict__ w_out, const float* __restrict__ b_out,
          const float* __restrict__ w_read, float* __restrict__ ws,
          float* __restrict__ out)
{
  __shared__ float sm[6][TELEMS];  // 36288 B -> 4 blocks/CU
  const int tid  = threadIdx.x;
  const int bid  = blockIdx.x;
  const int pg   = bid & 15;
  const int tile = bid >> 4;
  const int R0 = (tile >> 3) * 32;
  const int C0 = (tile & 7) * 32;
  const int trow = tid >> 3;
  const int tcol = (tid & 7) * 4;
  const int gidx = (R0 + trow) * RCdim + C0 + tcol;

  float acc[4] = {0.f,0.f,0.f,0.f};
  float v0[3][8], v1[3][8];

  // ==== Phase A: a = 4pg+2t -> low a, low a+1, high 64+2pg+t ====
#pragma unroll 1
  for (int t = 0; t < 2; ++t){
    const int a  = 4*pg + 2*t;
    const int ph = 64 + 2*pg + t;
    __syncthreads();
    stage4(x + (size_t)(2*a  )*IMG, sm[0], R0,C0,tid);
    stage4(x + (size_t)(2*a+1)*IMG, sm[1], R0,C0,tid);
    stage4(x + (size_t)(2*a+2)*IMG, sm[2], R0,C0,tid);
    stage4(x + (size_t)(2*a+3)*IMG, sm[3], R0,C0,tid);
    stage4(h + (size_t)(a    )*IMG, sm[4], R0,C0,tid);
    stage4(h + (size_t)(a+1  )*IMG, sm[5], R0,C0,tid);
    __syncthreads();

    float hc0[4], hc1[4], uH[4];
    { // high update conv (h_a, h_{a+1}); capture h centers for lows
      float wa[9], wb[9];
      load_w18(w_update + ph*18, wa, wb);
      const float b = b_update[ph];
      float uo[4] = {b,b,b,b};
      load8(sm[4], trow+1, tcol+2, v0);
      load8(sm[5], trow+1, tcol+2, v1);
      conv_acc<1>(v0, wa, uo); conv_acc<1>(v1, wb, uo);
#pragma unroll
      for (int k=0;k<4;++k){ hc0[k]=v0[1][k+2]; hc1[k]=v1[1][k+2]; uH[k]=sig_(uo[k]); }
    }
    float ns0[4], ns1[4];
    { // low plant a
      float wua[9],wub[9],woa[9],wob[9];
      load_w18(w_update + a*18, wua, wub);
      load_w18(w_out    + a*18, woa, wob);
      const float bu=b_update[a], bo=b_out[a];
      float uo[4]={bu,bu,bu,bu}, co[4]={bo,bo,bo,bo};
      load8(sm[0], trow+1, tcol+2, v0);
      load8(sm[1], trow+1, tcol+2, v1);
      conv_acc<1>(v0, wua, uo); conv_acc<1>(v1, wub, uo);
      conv_acc<1>(v0, woa, co); conv_acc<1>(v1, wob, co);
#pragma unroll
      for (int k=0;k<4;++k){ float u=sig_(uo[k]); ns0[k]=hc0[k]+u*(th_(co[k])-hc0[k]); }
    }
    { // low plant a+1
      float wua[9],wub[9],woa[9],wob[9];
      load_w18(w_update + (a+1)*18, wua, wub);
      load_w18(w_out    + (a+1)*18, woa, wob);
      const float bu=b_update[a+1], bo=b_out[a+1];
      float uo[4]={bu,bu,bu,bu}, co[4]={bo,bo,bo,bo};
      load8(sm[2], trow+1, tcol+2, v0);
      load8(sm[3], trow+1, tcol+2, v1);
      conv_acc<1>(v0, wua, uo); conv_acc<1>(v1, wub, uo);
      conv_acc<1>(v0, woa, co); conv_acc<1>(v1, wob, co);
#pragma unroll
      for (int k=0;k<4;++k){ float u=sig_(uo[k]); ns1[k]=hc1[k]+u*(th_(co[k])-hc1[k]); }
    }
    if (SPLIT){
      *(float4*)&ws[(size_t)a    *IMG + gidx] = make_float4(ns0[0],ns0[1],ns0[2],ns0[3]);
      *(float4*)&ws[(size_t)(a+1)*IMG + gidx] = make_float4(ns1[0],ns1[1],ns1[2],ns1[3]);
    } else {
#pragma unroll
      for (int k=0;k<4;++k){
        const float2 wv = *(const float2*)&w_read[(size_t)(gidx+k)*PCNT + a];
        acc[k] = fmaf(ns0[k], wv.x, fmaf(ns1[k], wv.y, acc[k]));
      }
    }
    float ga[2][4], gb[2][4];
    hr_compute(sm, w_reset, b_reset, a, tid, ga, gb);
    __syncthreads();
    hr_write(sm, tid, ga, gb);
    __syncthreads();
    { // high cand conv (hr pair) + blend
      float woa[9], wob[9];
      load_w18(w_out + ph*18, woa, wob);
      const float bo = b_out[ph];
      float co[4]={bo,bo,bo,bo};
      load8(sm[0], trow+1, tcol+2, v0);
      load8(sm[2], trow+1, tcol+2, v1);
      conv_acc<1>(v0, woa, co); conv_acc<1>(v1, wob, co);
      const float4 hp4 = *(const float4*)&h[(size_t)ph*IMG + gidx];
      const float hp[4] = {hp4.x,hp4.y,hp4.z,hp4.w};
      float nsH[4];
#pragma unroll
      for (int k=0;k<4;++k) nsH[k] = hp[k] + uH[k]*(th_(co[k])-hp[k]);
      if (SPLIT){
        *(float4*)&ws[(size_t)ph*IMG + gidx] = make_float4(nsH[0],nsH[1],nsH[2],nsH[3]);
      } else {
#pragma unroll
        for (int k=0;k<4;++k)
          acc[k] = fmaf(nsH[k], w_read[(size_t)(gidx+k)*PCNT + ph], acc[k]);
      }
    }
  }

  // ==== Phase B: a = 64+4pg+2t -> high plant 96+2pg+t ====
#pragma unroll 1
  for (int t = 0; t < 2; ++t){
    const int a    = 64 + 4*pg + 2*t;
    const int ph   = 96 + 2*pg + t;
    const int base = 8*pg + 4*t;
    __syncthreads();
    stage4(h + (size_t)(base  )*IMG, sm[0], R0,C0,tid);
    stage4(h + (size_t)(base+1)*IMG, sm[1], R0,C0,tid);
    stage4(h + (size_t)(base+2)*IMG, sm[2], R0,C0,tid);
    stage4(h + (size_t)(base+3)*IMG, sm[3], R0,C0,tid);
    stage4(h + (size_t)(a     )*IMG, sm[4], R0,C0,tid);
    stage4(h + (size_t)(a+1   )*IMG, sm[5], R0,C0,tid);
    __syncthreads();

    float uH[4];
    {
      float wa[9], wb[9];
      load_w18(w_update + ph*18, wa, wb);
      const float bu = b_update[ph];
      float uo[4] = {bu,bu,bu,bu};
      load8(sm[4], trow+1, tcol+2, v0);
      load8(sm[5], trow+1, tcol+2, v1);
      conv_acc<1>(v0, wa, uo); conv_acc<1>(v1, wb, uo);
#pragma unroll
      for (int k=0;k<4;++k) uH[k]=sig_(uo[k]);
    }
    float ga[2][4], gb[2][4];
    hr_compute(sm, w_reset, b_reset, a, tid, ga, gb);
    __syncthreads();
    hr_write(sm, tid, ga, gb);
    __syncthreads();
    {
      float wa[9], wb[9];
      load_w18(w_out + ph*18, wa, wb);
      const float bo = b_out[ph];
      float co[4] = {bo,bo,bo,bo};
      load8(sm[0], trow+1, tcol+2, v0);
      load8(sm[2], trow+1, tcol+2, v1);
      conv_acc<1>(v0, wa, co); conv_acc<1>(v1, wb, co);
      const float4 hp4 = *(const float4*)&h[(size_t)ph*IMG + gidx];
      const float hp[4] = {hp4.x,hp4.y,hp4.z,hp4.w};
      float nsH[4];
#pragma unroll
      for (int k=0;k<4;++k) nsH[k] = hp[k] + uH[k]*(th_(co[k])-hp[k]);
      if (SPLIT){
        *(float4*)&ws[(size_t)ph*IMG + gidx] = make_float4(nsH[0],nsH[1],nsH[2],nsH[3]);
      } else {
#pragma unroll
        for (int k=0;k<4;++k)
          acc[k] = fmaf(nsH[k], w_read[(size_t)(gidx+k)*PCNT + ph], acc[k]);
      }
    }
  }

  if (!SPLIT){
#pragma unroll
    for (int k=0;k<4;++k) atomicAdd(&out[gidx+k], acc[k]);
  }
}

extern "C" void kernel_launch(void* const* d_in, const int* in_sizes, int n_in,
                              void* d_out, int out_size, void* d_ws, size_t ws_size,
                              hipStream_t stream) {
  const float* x     = (const float*)d_in[0];
  const float* h     = (const float*)d_in[1];
  const float* wrst  = (const float*)d_in[2];
  const float* brst  = (const float*)d_in[3];
  const float* wupd  = (const float*)d_in[4];
  const float* bupd  = (const float*)d_in[5];
  const float* wout  = (const float*)d_in[6];
  const float* bout  = (const float*)d_in[7];
  const float* wread = (const float*)d_in[8];
  const float* bias  = (const float*)d_in[9];
  float* out = (float*)d_out;
  float* ws  = (float*)d_ws;

  const bool split = ws_size >= (size_t)PCNT * IMG * sizeof(float);
  if (split){
    hipLaunchKernelGGL(gru_fused<true>, dim3(64*16), dim3(NTHREADS), 0, stream,
                       x, h, wrst, brst, wupd, bupd, wout, bout, wread, ws, out);
    hipLaunchKernelGGL(reduce_out, dim3(IMG/NTHREADS), dim3(NTHREADS), 0, stream,
                       ws, wread, bias, out);
  } else {
    hipLaunchKernelGGL(init_out, dim3(IMG/NTHREADS), dim3(NTHREADS), 0, stream, bias, out);
    hipLaunchKernelGGL(gru_fused<false>, dim3(64*16), dim3(NTHREADS), 0, stream,
                       x, h, wrst, brst, wupd, bupd, wout, bout, wread, ws, out);
  }
}